// Round 8
// baseline (1278.839 us; speedup 1.0000x reference)
//
#include <hip/hip_runtime.h>
#include <stdint.h>

#define D_DIM 1024     // D_IN == D_MODEL == 1024
#define BT    32768    // 8*4096
#define NCHUNK 32      // 4096/128 chunks per batch
#define NT    32       // K-tiles of 32

typedef __attribute__((ext_vector_type(8))) short short8;
typedef __attribute__((ext_vector_type(4))) float f32x4;

__device__ __forceinline__ ushort f2bf(float f) {
  union { float f; uint32_t u; } v; v.f = f;
  uint32_t u = v.u + 0x7fffu + ((v.u >> 16) & 1u);
  return (ushort)(u >> 16);
}

// ---------------- x (B,T,1024) fp32 -> bf16 ----------------
__global__ void cvt_x_kernel(const float4* __restrict__ x, ushort4* __restrict__ o, int n4) {
  int i = blockIdx.x * blockDim.x + threadIdx.x;
  if (i < n4) {
    float4 f = x[i];
    ushort4 r;
    r.x = f2bf(f.x); r.y = f2bf(f.y); r.z = f2bf(f.z); r.w = f2bf(f.w);
    o[i] = r;
  }
}

// ---------------- W (K,N) fp32 -> WT (3,N,K) bf16 ----------------
__global__ void transpose_w_kernel(const float* __restrict__ W0, const float* __restrict__ W1,
                                   const float* __restrict__ W2, ushort* __restrict__ WT) {
  __shared__ float tile[32][33];
  const float* W = (blockIdx.z == 0) ? W0 : ((blockIdx.z == 1) ? W1 : W2);
  int x0 = blockIdx.x * 32, y0 = blockIdx.y * 32;
  for (int i = threadIdx.y; i < 32; i += 8)
    tile[i][threadIdx.x] = W[(size_t)(y0 + i) * D_DIM + x0 + threadIdx.x];
  __syncthreads();
  ushort* O = WT + (size_t)blockIdx.z * D_DIM * D_DIM;
  for (int i = threadIdx.y; i < 32; i += 8)
    O[(size_t)(x0 + i) * D_DIM + y0 + threadIdx.x] = f2bf(tile[threadIdx.x][i]);
}

// ---------------- fused GEMM(x3) + pointwise + chunk scan ----------------
__device__ __forceinline__ void async16(const void* g, void* l) {
  __builtin_amdgcn_global_load_lds((const __attribute__((address_space(1))) void*)g,
                                   (__attribute__((address_space(3))) void*)l, 16, 0, 0);
}

__device__ __forceinline__ float softplusf(float x) {
  return fmaxf(x, 0.f) + log1pf(expf(-fabsf(x)));
}

// Block: 256 threads (4 waves, 2x2). Tile 128(t) x 64(d), BK=32, double-buffered.
// LDS per buffer: x [128][32]bf16 = 8KB, W [3][64][32]bf16 = 12KB -> 20KB; dbuf 40KB.
// Swizzle (rule 21, both-sides): linear LDS dest, global src slot = (c&3)^((c>>3)&3),
// read slot = lhi ^ ((llo>>1)&3). Kills the 8-way row-stride-64B conflict.
__global__ __launch_bounds__(256, 2) void gemm_scan_kernel(
    const ushort* __restrict__ xb, const ushort* __restrict__ wt,
    const float* __restrict__ b_lam, const float* __restrict__ b_del,
    const float* __restrict__ b_B, float* __restrict__ Ac, float* __restrict__ Sc) {
  __shared__ __align__(16) char smem[40960];
  const int tid  = threadIdx.x;
  const int lane = tid & 63, wid = tid >> 6;
  const int wr = wid >> 1, wc = wid & 1;
  const int lhi = lane >> 4, llo = lane & 15;
  const int M0 = blockIdx.x * 128, N0 = blockIdx.y * 64;
  const int slotx = (llo >> 1) & 3;          // read-side XOR (row-dependent part, llo-only)

  f32x4 acc[3][4][2];
#pragma unroll
  for (int g = 0; g < 3; ++g)
#pragma unroll
    for (int fr = 0; fr < 4; ++fr)
#pragma unroll
      for (int fc = 0; fc < 2; ++fc)
        acc[g][fr][fc] = (f32x4){0.f, 0.f, 0.f, 0.f};

  // Pre-swizzled per-lane global sources (k0 added per tile).
  const int cx0 = tid, cx1 = 256 + tid;
  const ushort* gx0 = xb + (size_t)(M0 + (cx0 >> 2)) * D_DIM + ((cx0 & 3) ^ ((cx0 >> 3) & 3)) * 8;
  const ushort* gx1 = xb + (size_t)(M0 + (cx1 >> 2)) * D_DIM + ((cx1 & 3) ^ ((cx1 >> 3) & 3)) * 8;
  const ushort* gw0 = wt + (size_t)(0 * D_DIM + N0 + (tid >> 2)) * D_DIM + ((tid & 3) ^ ((tid >> 3) & 3)) * 8;
  const ushort* gw1 = wt + (size_t)(1 * D_DIM + N0 + (tid >> 2)) * D_DIM + ((tid & 3) ^ ((tid >> 3) & 3)) * 8;
  const ushort* gw2 = wt + (size_t)(2 * D_DIM + N0 + (tid >> 2)) * D_DIM + ((tid & 3) ^ ((tid >> 3) & 3)) * 8;
  const int wbase = wid * 1024;   // (wid*64 chunks)*16B

  // Prologue: stage tile 0 into buf0, drain, barrier.
  async16(gx0, smem + wbase);
  async16(gx1, smem + 4096 + wbase);
  async16(gw0, smem + 8192 + wbase);
  async16(gw1, smem + 12288 + wbase);
  async16(gw2, smem + 16384 + wbase);
  __syncthreads();

  for (int t = 0; t < NT; ++t) {
    const int cur = t & 1;
    // Prefetch next tile into the other buffer BEFORE compute (loads fly under MFMA).
    if (t + 1 < NT) {
      char* nb = smem + (cur ^ 1) * 20480;
      const int ko = (t + 1) * 32;
      async16(gx0 + ko, nb + wbase);
      async16(gx1 + ko, nb + 4096 + wbase);
      async16(gw0 + ko, nb + 8192 + wbase);
      async16(gw1 + ko, nb + 12288 + wbase);
      async16(gw2 + ko, nb + 16384 + wbase);
    }
    const char* xs  = smem + cur * 20480;
    const char* wsm = xs + 8192;
    short8 af[4];
#pragma unroll
    for (int fr = 0; fr < 4; ++fr) {
      int r = wr * 64 + fr * 16 + llo;
      af[fr] = *(const short8*)(xs + r * 64 + ((lhi ^ slotx) << 4));
    }
    short8 bfr[3][2];
#pragma unroll
    for (int g = 0; g < 3; ++g)
#pragma unroll
      for (int fc = 0; fc < 2; ++fc) {
        int n = wc * 32 + fc * 16 + llo;
        bfr[g][fc] = *(const short8*)(wsm + g * 4096 + n * 64 + ((lhi ^ slotx) << 4));
      }
#pragma unroll
    for (int g = 0; g < 3; ++g)
#pragma unroll
      for (int fr = 0; fr < 4; ++fr)
#pragma unroll
        for (int fc = 0; fc < 2; ++fc)
          acc[g][fr][fc] = __builtin_amdgcn_mfma_f32_16x16x32_bf16(
              af[fr], bfr[g][fc], acc[g][fr][fc], 0, 0, 0);
    __syncthreads();   // drains vmcnt(0)+lgkmcnt(0): staged tile visible, reads done
  }

  // Epilogue: two 64-row halves; alpha/drive in LDS [64][66] (stride-66 kills
  // write conflicts), segmented scan: 4 segs x 64 cols, 16 rows each, then fold.
  float* la  = (float*)smem;               // [64][66] f32 = 16896 B
  float* ldv = (float*)(smem + 16896);     // [64][66]
  float* Asg = (float*)(smem + 33792);     // [4][64]
  float* Ssg = (float*)(smem + 34816);     // [4][64]
  const int colt = tid & 63, seg = tid >> 6;
  float A = 1.f, S = 0.f;                  // running per-column state (tid<64)
#pragma unroll
  for (int half = 0; half < 2; ++half) {
    __syncthreads();
    if (wr == half) {
#pragma unroll
      for (int fc = 0; fc < 2; ++fc) {
        int col = wc * 32 + fc * 16 + llo;
        int d = N0 + col;
        float bl = b_lam[d], bd = b_del[d], bu = b_B[d];
#pragma unroll
        for (int fr = 0; fr < 4; ++fr) {
#pragma unroll
          for (int j = 0; j < 4; ++j) {
            int row = fr * 16 + lhi * 4 + j;   // local row within half
            float lam = softplusf(acc[0][fr][fc][j] + bl);
            float de  = softplusf(acc[1][fr][fc][j] + bd);
            float uu  = acc[2][fr][fc][j] + bu;
            la[row * 66 + col]  = expf(-de * lam);
            ldv[row * 66 + col] = de * uu;
          }
        }
      }
    }
    __syncthreads();
    // Segmented scan: thread (seg, colt) scans rows [seg*16, seg*16+16).
    float a_ = 1.f, s_ = 0.f;
#pragma unroll 4
    for (int i = 0; i < 16; ++i) {
      float av = la[(seg * 16 + i) * 66 + colt];
      float dv = ldv[(seg * 16 + i) * 66 + colt];
      s_ = fmaf(av, s_, dv);
      a_ *= av;
    }
    Asg[seg * 64 + colt] = a_;
    Ssg[seg * 64 + colt] = s_;
    __syncthreads();
    if (tid < 64) {
#pragma unroll
      for (int sgi = 0; sgi < 4; ++sgi) {
        float av = Asg[sgi * 64 + tid], sv = Ssg[sgi * 64 + tid];
        S = fmaf(av, S, sv);
        A *= av;
      }
    }
  }
  if (tid < 64) {
    int b  = M0 >> 12;          // 4096 rows per batch
    int cb = (M0 >> 7) & 31;    // chunk within batch
    size_t o = (size_t)(b * NCHUNK + cb) * D_DIM + N0 + tid;
    Ac[o] = A;
    Sc[o] = S;
  }
}

// ---------------- cross-chunk combine + output projections ----------------
__global__ __launch_bounds__(1024) void combine_project_kernel(
    const float* __restrict__ Ac, const float* __restrict__ Sc,
    const float* __restrict__ Wpar, const float* __restrict__ bpar,
    const float* __restrict__ Wadd, const float* __restrict__ badd,
    float* __restrict__ out) {
  int b = blockIdx.x, d = threadIdx.x;
  size_t base = (size_t)b * NCHUNK * D_DIM + d;
  float s = 0.f;
#pragma unroll 4
  for (int c = 0; c < NCHUNK; ++c)
    s = fmaf(Ac[base + (size_t)c * D_DIM], s, Sc[base + (size_t)c * D_DIM]);
  float p0 = s * Wpar[2 * d], p1 = s * Wpar[2 * d + 1], pa = s * Wadd[d];
#pragma unroll
  for (int off = 32; off; off >>= 1) {
    p0 += __shfl_xor(p0, off, 64);
    p1 += __shfl_xor(p1, off, 64);
    pa += __shfl_xor(pa, off, 64);
  }
  __shared__ float r0[16], r1[16], r2[16];
  int wid = threadIdx.x >> 6, lane = threadIdx.x & 63;
  if (lane == 0) { r0[wid] = p0; r1[wid] = p1; r2[wid] = pa; }
  __syncthreads();
  if (threadIdx.x == 0) {
    float a = bpar[0], bb = bpar[1], cc = badd[0];
    for (int i = 0; i < 16; ++i) { a += r0[i]; bb += r1[i]; cc += r2[i]; }
    out[b * 2 + 0] = a;       // parity_logits (8,2) flat first
    out[b * 2 + 1] = bb;
    out[16 + b]    = cc;      // add_pred (8,1) after
  }
}

extern "C" void kernel_launch(void* const* d_in, const int* in_sizes, int n_in,
                              void* d_out, int out_size, void* d_ws, size_t ws_size,
                              hipStream_t stream) {
  const float* x     = (const float*)d_in[0];
  const float* W_lam = (const float*)d_in[1];
  const float* b_lam = (const float*)d_in[2];
  const float* W_del = (const float*)d_in[3];
  const float* b_del = (const float*)d_in[4];
  const float* W_B   = (const float*)d_in[5];
  const float* b_B   = (const float*)d_in[6];
  const float* W_par = (const float*)d_in[7];
  const float* b_par = (const float*)d_in[8];
  const float* W_add = (const float*)d_in[9];
  const float* b_add = (const float*)d_in[10];

  char* ws = (char*)d_ws;
  ushort* xb = (ushort*)ws;                          // 64 MB bf16 x
  ushort* wt = (ushort*)(ws + 67108864);             // 6 MB  bf16 WT[3][n][k]
  float*  Ac = (float*)(ws + 73400320);              // 1 MB  chunk A
  float*  Sc = (float*)(ws + 74448896);              // 1 MB  chunk S

  int n4 = (BT * D_DIM) / 4;   // 8388608
  cvt_x_kernel<<<n4 / 256, 256, 0, stream>>>((const float4*)x, (ushort4*)xb, n4);
  transpose_w_kernel<<<dim3(32, 32, 3), dim3(32, 8, 1), 0, stream>>>(W_lam, W_del, W_B, wt);
  gemm_scan_kernel<<<dim3(BT / 128, D_DIM / 64), 256, 0, stream>>>(
      xb, wt, b_lam, b_del, b_B, Ac, Sc);
  combine_project_kernel<<<8, 1024, 0, stream>>>(Ac, Sc, W_par, b_par, W_add, b_add,
                                                 (float*)d_out);
}

// Round 11
// 454.763 us; speedup vs baseline: 2.8121x; 2.8121x over previous
//
#include <hip/hip_runtime.h>
#include <stdint.h>

#define D_DIM 1024     // D_IN == D_MODEL == 1024
#define BT    32768    // 8*4096
#define NCHUNK 32      // 4096/128 chunks per batch
#define NT    32       // K-tiles of 32

typedef __attribute__((ext_vector_type(8))) short short8;
typedef __attribute__((ext_vector_type(4))) float f32x4;

__device__ __forceinline__ ushort f2bf(float f) {
  union { float f; uint32_t u; } v; v.f = f;
  uint32_t u = v.u + 0x7fffu + ((v.u >> 16) & 1u);
  return (ushort)(u >> 16);
}

// ---------------- x (B,T,1024) fp32 -> bf16 ----------------
__global__ void cvt_x_kernel(const float4* __restrict__ x, ushort4* __restrict__ o, int n4) {
  int i = blockIdx.x * blockDim.x + threadIdx.x;
  if (i < n4) {
    float4 f = x[i];
    ushort4 r;
    r.x = f2bf(f.x); r.y = f2bf(f.y); r.z = f2bf(f.z); r.w = f2bf(f.w);
    o[i] = r;
  }
}

// ---------------- W (K,N) fp32 -> WT (3,N,K) bf16 ----------------
__global__ void transpose_w_kernel(const float* __restrict__ W0, const float* __restrict__ W1,
                                   const float* __restrict__ W2, ushort* __restrict__ WT) {
  __shared__ float tile[32][33];
  const float* W = (blockIdx.z == 0) ? W0 : ((blockIdx.z == 1) ? W1 : W2);
  int x0 = blockIdx.x * 32, y0 = blockIdx.y * 32;
  for (int i = threadIdx.y; i < 32; i += 8)
    tile[i][threadIdx.x] = W[(size_t)(y0 + i) * D_DIM + x0 + threadIdx.x];
  __syncthreads();
  ushort* O = WT + (size_t)blockIdx.z * D_DIM * D_DIM;
  for (int i = threadIdx.y; i < 32; i += 8)
    O[(size_t)(x0 + i) * D_DIM + y0 + threadIdx.x] = f2bf(tile[threadIdx.x][i]);
}

// ---------------- fused GEMM(x3) + pointwise + chunk scan ----------------
__device__ __forceinline__ void async16(const void* g, void* l) {
  __builtin_amdgcn_global_load_lds((const __attribute__((address_space(1))) void*)g,
                                   (__attribute__((address_space(3))) void*)l, 16, 0, 0);
}

// fast softplus: threshold 5e-2, margin ~6x; __expf/__logf are single-instr class
__device__ __forceinline__ float softplusf(float x) {
  return fmaxf(x, 0.f) + __logf(1.f + __expf(-fabsf(x)));
}

// Block: 256 threads (4 waves, 2x2). Tile 128(t) x 64(d), BK=32.
// MEASURED-GOOD round-3 structure (2 barriers, single buffer — m97-style; the
// r5 dbuf+1-barrier regressed 2x via compiler alias-conservatism on runtime cur).
// Grafts vs r3 (each measured good in r8): hoisted swizzled global ptrs (VALU
// 55->27%), both-sides XOR swizzle (conflicts 2.3e7->2.1e6), fast softplus.
__global__ __launch_bounds__(256, 2) void gemm_scan_kernel(
    const ushort* __restrict__ xb, const ushort* __restrict__ wt,
    const float* __restrict__ b_lam, const float* __restrict__ b_del,
    const float* __restrict__ b_B, float* __restrict__ Ac, float* __restrict__ Sc) {
  __shared__ __align__(16) char smem[35840];
  const int tid  = threadIdx.x;
  const int lane = tid & 63, wid = tid >> 6;
  const int wr = wid >> 1, wc = wid & 1;
  const int lhi = lane >> 4, llo = lane & 15;
  const int M0 = blockIdx.x * 128, N0 = blockIdx.y * 64;
  const int slotx = (llo >> 1) & 3;          // read-side XOR (row-dependent part)

  f32x4 acc[3][4][2];
#pragma unroll
  for (int g = 0; g < 3; ++g)
#pragma unroll
    for (int fr = 0; fr < 4; ++fr)
#pragma unroll
      for (int fc = 0; fc < 2; ++fc)
        acc[g][fr][fc] = (f32x4){0.f, 0.f, 0.f, 0.f};

  // Pre-swizzled per-lane global sources, hoisted out of the K-loop.
  // Staging chunk c = row (c>>2), slot (c&3); src k-chunk = slot ^ ((row>>1)&3).
  const int cx0 = tid, cx1 = 256 + tid;
  const ushort* gx0 = xb + (size_t)(M0 + (cx0 >> 2)) * D_DIM + ((cx0 & 3) ^ ((cx0 >> 3) & 3)) * 8;
  const ushort* gx1 = xb + (size_t)(M0 + (cx1 >> 2)) * D_DIM + ((cx1 & 3) ^ ((cx1 >> 3) & 3)) * 8;
  const ushort* gw0 = wt + (size_t)(0 * D_DIM + N0 + (tid >> 2)) * D_DIM + ((tid & 3) ^ ((tid >> 3) & 3)) * 8;
  const ushort* gw1 = wt + (size_t)(1 * D_DIM + N0 + (tid >> 2)) * D_DIM + ((tid & 3) ^ ((tid >> 3) & 3)) * 8;
  const ushort* gw2 = wt + (size_t)(2 * D_DIM + N0 + (tid >> 2)) * D_DIM + ((tid & 3) ^ ((tid >> 3) & 3)) * 8;
  const int wbase = wid * 1024;   // (wid*64 chunks)*16B

  for (int t = 0; t < NT; ++t) {
    const int ko = t * 32;
    __syncthreads();   // previous iter's frag reads done before overwrite
    async16(gx0 + ko, smem + wbase);
    async16(gx1 + ko, smem + 4096 + wbase);
    async16(gw0 + ko, smem + 8192 + wbase);
    async16(gw1 + ko, smem + 12288 + wbase);
    async16(gw2 + ko, smem + 16384 + wbase);
    __syncthreads();   // compiler drains vmcnt before s_barrier -> staged data visible

    const char* xs  = smem;
    const char* wsm = smem + 8192;
    short8 af[4];
#pragma unroll
    for (int fr = 0; fr < 4; ++fr) {
      int r = wr * 64 + fr * 16 + llo;
      af[fr] = *(const short8*)(xs + r * 64 + ((lhi ^ slotx) << 4));
    }
    short8 bfr[3][2];
#pragma unroll
    for (int g = 0; g < 3; ++g)
#pragma unroll
      for (int fc = 0; fc < 2; ++fc) {
        int n = wc * 32 + fc * 16 + llo;
        bfr[g][fc] = *(const short8*)(wsm + g * 4096 + n * 64 + ((lhi ^ slotx) << 4));
      }
#pragma unroll
    for (int g = 0; g < 3; ++g)
#pragma unroll
      for (int fr = 0; fr < 4; ++fr)
#pragma unroll
        for (int fc = 0; fc < 2; ++fc)
          acc[g][fr][fc] = __builtin_amdgcn_mfma_f32_16x16x32_bf16(
              af[fr], bfr[g][fc], acc[g][fr][fc], 0, 0, 0);
  }
  __syncthreads();   // all frag reads done before epilogue overwrites LDS

  // Epilogue: two 64-row halves; alpha/drive in LDS [64][66] (stride-66 kills
  // write conflicts), segmented scan: 4 segs x 64 cols, 16 rows each, then fold.
  float* la  = (float*)smem;               // [64][66] f32 = 16896 B
  float* ldv = (float*)(smem + 16896);     // [64][66]
  float* Asg = (float*)(smem + 33792);     // [4][64]
  float* Ssg = (float*)(smem + 34816);     // [4][64]
  const int colt = tid & 63, seg = tid >> 6;
  float A = 1.f, S = 0.f;                  // running per-column state (tid<64)
#pragma unroll
  for (int half = 0; half < 2; ++half) {
    __syncthreads();
    if (wr == half) {
#pragma unroll
      for (int fc = 0; fc < 2; ++fc) {
        int col = wc * 32 + fc * 16 + llo;
        int d = N0 + col;
        float bl = b_lam[d], bd = b_del[d], bu = b_B[d];
#pragma unroll
        for (int fr = 0; fr < 4; ++fr) {
#pragma unroll
          for (int j = 0; j < 4; ++j) {
            int row = fr * 16 + lhi * 4 + j;   // local row within half
            float lam = softplusf(acc[0][fr][fc][j] + bl);
            float de  = softplusf(acc[1][fr][fc][j] + bd);
            float uu  = acc[2][fr][fc][j] + bu;
            la[row * 66 + col]  = __expf(-de * lam);
            ldv[row * 66 + col] = de * uu;
          }
        }
      }
    }
    __syncthreads();
    // Segmented scan: thread (seg, colt) scans rows [seg*16, seg*16+16).
    float a_ = 1.f, s_ = 0.f;
#pragma unroll 4
    for (int i = 0; i < 16; ++i) {
      float av = la[(seg * 16 + i) * 66 + colt];
      float dv = ldv[(seg * 16 + i) * 66 + colt];
      s_ = fmaf(av, s_, dv);
      a_ *= av;
    }
    Asg[seg * 64 + colt] = a_;
    Ssg[seg * 64 + colt] = s_;
    __syncthreads();
    if (tid < 64) {
#pragma unroll
      for (int sgi = 0; sgi < 4; ++sgi) {
        float av = Asg[sgi * 64 + tid], sv = Ssg[sgi * 64 + tid];
        S = fmaf(av, S, sv);
        A *= av;
      }
    }
  }
  if (tid < 64) {
    int b  = M0 >> 12;          // 4096 rows per batch
    int cb = (M0 >> 7) & 31;    // chunk within batch
    size_t o = (size_t)(b * NCHUNK + cb) * D_DIM + N0 + tid;
    Ac[o] = A;
    Sc[o] = S;
  }
}

// ---------------- cross-chunk combine + output projections ----------------
__global__ __launch_bounds__(1024) void combine_project_kernel(
    const float* __restrict__ Ac, const float* __restrict__ Sc,
    const float* __restrict__ Wpar, const float* __restrict__ bpar,
    const float* __restrict__ Wadd, const float* __restrict__ badd,
    float* __restrict__ out) {
  int b = blockIdx.x, d = threadIdx.x;
  size_t base = (size_t)b * NCHUNK * D_DIM + d;
  float s = 0.f;
#pragma unroll 4
  for (int c = 0; c < NCHUNK; ++c)
    s = fmaf(Ac[base + (size_t)c * D_DIM], s, Sc[base + (size_t)c * D_DIM]);
  float p0 = s * Wpar[2 * d], p1 = s * Wpar[2 * d + 1], pa = s * Wadd[d];
#pragma unroll
  for (int off = 32; off; off >>= 1) {
    p0 += __shfl_xor(p0, off, 64);
    p1 += __shfl_xor(p1, off, 64);
    pa += __shfl_xor(pa, off, 64);
  }
  __shared__ float r0[16], r1[16], r2[16];
  int wid = threadIdx.x >> 6, lane = threadIdx.x & 63;
  if (lane == 0) { r0[wid] = p0; r1[wid] = p1; r2[wid] = pa; }
  __syncthreads();
  if (threadIdx.x == 0) {
    float a = bpar[0], bb = bpar[1], cc = badd[0];
    for (int i = 0; i < 16; ++i) { a += r0[i]; bb += r1[i]; cc += r2[i]; }
    out[b * 2 + 0] = a;       // parity_logits (8,2) flat first
    out[b * 2 + 1] = bb;
    out[16 + b]    = cc;      // add_pred (8,1) after
  }
}

extern "C" void kernel_launch(void* const* d_in, const int* in_sizes, int n_in,
                              void* d_out, int out_size, void* d_ws, size_t ws_size,
                              hipStream_t stream) {
  const float* x     = (const float*)d_in[0];
  const float* W_lam = (const float*)d_in[1];
  const float* b_lam = (const float*)d_in[2];
  const float* W_del = (const float*)d_in[3];
  const float* b_del = (const float*)d_in[4];
  const float* W_B   = (const float*)d_in[5];
  const float* b_B   = (const float*)d_in[6];
  const float* W_par = (const float*)d_in[7];
  const float* b_par = (const float*)d_in[8];
  const float* W_add = (const float*)d_in[9];
  const float* b_add = (const float*)d_in[10];

  char* ws = (char*)d_ws;
  ushort* xb = (ushort*)ws;                          // 64 MB bf16 x
  ushort* wt = (ushort*)(ws + 67108864);             // 6 MB  bf16 WT[3][n][k]
  float*  Ac = (float*)(ws + 73400320);              // 1 MB  chunk A
  float*  Sc = (float*)(ws + 74448896);              // 1 MB  chunk S

  int n4 = (BT * D_DIM) / 4;   // 8388608
  cvt_x_kernel<<<n4 / 256, 256, 0, stream>>>((const float4*)x, (ushort4*)xb, n4);
  transpose_w_kernel<<<dim3(32, 32, 3), dim3(32, 8, 1), 0, stream>>>(W_lam, W_del, W_B, wt);
  gemm_scan_kernel<<<dim3(BT / 128, D_DIM / 64), 256, 0, stream>>>(
      xb, wt, b_lam, b_del, b_B, Ac, Sc);
  combine_project_kernel<<<8, 1024, 0, stream>>>(Ac, Sc, W_par, b_par, W_add, b_add,
                                                 (float*)d_out);
}